// Round 10
// baseline (115.380 us; speedup 1.0000x reference)
//
#include <hip/hip_runtime.h>

// ---- problem constants ----
#define NB 8192      // batch rows
#define NM 1024      // image dim
#define NK 2048      // dictionary size

typedef unsigned short ushort_t;
using bf16x8 = __attribute__((ext_vector_type(8))) short;
using f32x4  = __attribute__((ext_vector_type(4))) float;

// T = 101 provably: accept at t=101 holds for all b/a > 0; flip at t=100
// would need b/a >= ~4e6 but b/a <= tr(W W^T) = 2048 (unit-norm cols).
__device__ __forceinline__ float alpha_const() {
  const double s = 0.1 * (2.0 / 8388608.0);
  return (float)(101.0 * s);
}

__device__ __forceinline__ ushort_t f2bf(float f) {
  union { float f; unsigned u; } v; v.f = f;
  unsigned r = (v.u + 0x7FFFu + ((v.u >> 16) & 1u)) >> 16;  // RNE
  return (ushort_t)r;
}

__device__ __forceinline__ void gload_lds16(const void* g, void* l) {
  __builtin_amdgcn_global_load_lds(
      (const __attribute__((address_space(1))) unsigned int*)g,
      (__attribute__((address_space(3))) unsigned int*)l, 16, 0, 0);
}

// ===== fused prep: img->bf16 (0-511), W->Wt transpose (512-1023),
//       Q = bf16(W @ W^T) from f32 W directly (1024-1279) =====================
__global__ __launch_bounds__(256)
void prep_k(const float* __restrict__ img, const float* __restrict__ W,
            ushort_t* __restrict__ imgbf, ushort_t* __restrict__ Wt,
            ushort_t* __restrict__ Qbf)
{
  __shared__ __align__(128) char smem[16640];
  const int tid = threadIdx.x;
  const int b = blockIdx.x;

  if (b < 512) {
    // ---- img -> bf16, 512 blocks x 16 float4/thread ----
    const int base = b * 4096;
#pragma unroll
    for (int i = 0; i < 16; ++i) {
      const int idx = base + i * 256 + tid;
      const float4 v = ((const float4*)img)[idx];
      ushort4 o;
      o.x = f2bf(v.x); o.y = f2bf(v.y); o.z = f2bf(v.z); o.w = f2bf(v.w);
      ((ushort4*)imgbf)[idx] = o;
    }
  } else if (b < 1024) {
    // ---- W 64x64 tile transpose -> Wt (512 tiles: 16m x 32k) ----
    ushort_t (*tile)[65] = (ushort_t(*)[65])smem;
    const int bW = b - 512;
    const int m0 = (bW >> 5) * 64, k0 = (bW & 31) * 64;
    const int r = tid >> 2, q = tid & 3;
    ushort_t loc[16];
#pragma unroll
    for (int j = 0; j < 4; ++j) {
      const float4 v = *(const float4*)&W[(size_t)(m0 + r) * NK + k0 + q * 16 + j * 4];
      loc[j * 4 + 0] = f2bf(v.x); loc[j * 4 + 1] = f2bf(v.y);
      loc[j * 4 + 2] = f2bf(v.z); loc[j * 4 + 3] = f2bf(v.w);
    }
#pragma unroll
    for (int jj = 0; jj < 16; ++jj) tile[r][q * 16 + jj] = loc[jj];
    __syncthreads();
    const int kk = tid >> 2, qq = tid & 3;
#pragma unroll
    for (int j = 0; j < 4; ++j) {
      ushort4 o;
      o.x = tile[qq * 16 + j * 4 + 0][kk];
      o.y = tile[qq * 16 + j * 4 + 1][kk];
      o.z = tile[qq * 16 + j * 4 + 2][kk];
      o.w = tile[qq * 16 + j * 4 + 3][kk];
      *(ushort4*)&Wt[(size_t)(k0 + kk) * NM + m0 + qq * 16 + j * 4] = o;
    }
  } else {
    // ---- Q tile (64x64): reads W f32, converts with f2bf (bitwise == Wbf),
    //      same [64][64] LDS layout + MFMA K-order as prior qk64 -> Q bitwise.
    ushort_t* As = (ushort_t*)smem;            // [64][64]
    ushort_t* Bs = (ushort_t*)(smem + 8192);   // [64][64]
    const int bq = b - 1024;                   // 16 x 16 tiles
    const int i0 = (bq >> 4) * 64, j0 = (bq & 15) * 64;
    const int w = tid >> 6, l = tid & 63;
    const int wm2 = w >> 1, wn2 = w & 1;
    const int l15 = l & 15, l16 = l >> 4;
    const int r = tid >> 2, q4 = tid & 3;

    f32x4 acc[2][2];
#pragma unroll
    for (int m = 0; m < 2; ++m)
#pragma unroll
      for (int n = 0; n < 2; ++n)
        acc[m][n] = (f32x4){0.f, 0.f, 0.f, 0.f};

    for (int k0 = 0; k0 < NK; k0 += 64) {
      ushort_t la[16], lb[16];
      const float* pa = W + (size_t)(i0 + r) * NK + k0 + q4 * 16;
      const float* pb = W + (size_t)(j0 + r) * NK + k0 + q4 * 16;
#pragma unroll
      for (int j = 0; j < 4; ++j) {
        const float4 va = *(const float4*)(pa + j * 4);
        la[j * 4 + 0] = f2bf(va.x); la[j * 4 + 1] = f2bf(va.y);
        la[j * 4 + 2] = f2bf(va.z); la[j * 4 + 3] = f2bf(va.w);
        const float4 vb = *(const float4*)(pb + j * 4);
        lb[j * 4 + 0] = f2bf(vb.x); lb[j * 4 + 1] = f2bf(vb.y);
        lb[j * 4 + 2] = f2bf(vb.z); lb[j * 4 + 3] = f2bf(vb.w);
      }
      __syncthreads();   // prior MFMA reads done before overwrite
#pragma unroll
      for (int j = 0; j < 4; ++j) {
        ushort4 oa, ob;
        oa.x = la[j * 4 + 0]; oa.y = la[j * 4 + 1];
        oa.z = la[j * 4 + 2]; oa.w = la[j * 4 + 3];
        ob.x = lb[j * 4 + 0]; ob.y = lb[j * 4 + 1];
        ob.z = lb[j * 4 + 2]; ob.w = lb[j * 4 + 3];
        *(ushort4*)&As[r * 64 + q4 * 16 + j * 4] = oa;
        *(ushort4*)&Bs[r * 64 + q4 * 16 + j * 4] = ob;
      }
      __syncthreads();
#pragma unroll
      for (int ks = 0; ks < 2; ++ks) {
        bf16x8 af[2], bfr[2];
#pragma unroll
        for (int m = 0; m < 2; ++m)
          af[m] = *(const bf16x8*)&As[(wm2 * 32 + m * 16 + l15) * 64 + ks * 32 + l16 * 8];
#pragma unroll
        for (int n = 0; n < 2; ++n)
          bfr[n] = *(const bf16x8*)&Bs[(wn2 * 32 + n * 16 + l15) * 64 + ks * 32 + l16 * 8];
#pragma unroll
        for (int m = 0; m < 2; ++m)
#pragma unroll
          for (int n = 0; n < 2; ++n)
            acc[m][n] = __builtin_amdgcn_mfma_f32_16x16x32_bf16(af[m], bfr[n], acc[m][n], 0, 0, 0);
      }
    }
    __syncthreads();
    // C/D layout: col = lane&15, row = (lane>>4)*4 + q
#pragma unroll
    for (int m = 0; m < 2; ++m)
#pragma unroll
      for (int n = 0; n < 2; ++n) {
        const int gr0 = i0 + wm2 * 32 + m * 16 + l16 * 4;
        const int gc  = j0 + wn2 * 32 + n * 16 + l15;
#pragma unroll
        for (int q = 0; q < 4; ++q)
          Qbf[(size_t)(gr0 + q) * NM + gc] = f2bf(acc[m][n][q]);
      }
  }
}

// ============== fused finals: C = imgbf @ Bcat^T, 256x256 tiles ==============
// Bcat = [Wt (2048 rows) ; Q (1024 rows)], KK=1024. Grid 32 x 12.
// bj<8 -> r-region (ld 2048); bj>=8 -> pred-region (ld 1024). Both bitwise ==
// the separate launches (per-element K-accumulation order unchanged).
// 8-phase schedule: {ds_read | stage 1 half-tile | barrier | lgkmcnt(0) |
// setprio+16 MFMA | [vmcnt(4) at ph4/ph8] | barrier}; last iter peeled with
// store-overlap. XOR swizzle byte^=(row&7)<<4 (inv-swizzled src, swizzled read).
__global__ __launch_bounds__(512, 2)
void gemm8ph(const ushort_t* __restrict__ Aop, const ushort_t* __restrict__ Bcat,
             int KK, int njb, float* __restrict__ outR, float* __restrict__ outP)
{
  constexpr int BN = 256, WN = 64, NFR = 4;

  const int tid = threadIdx.x;
  const int w = tid >> 6, l = tid & 63;
  const int wm = w >> 2, wn = w & 3;
  // XCD-aware swizzle (grid % 8 == 0)
  const int wg = (blockIdx.x & 7) * ((int)gridDim.x >> 3) + ((int)blockIdx.x >> 3);
  const int bi = wg / njb, bj = wg % njb;
  const int i0 = bi * 256;
  const int j0cat = bj * BN;                 // row into Bcat (0..3071)
  float* outf; int outld, j0;
  if (bj < 8) { outf = outR; outld = NK; j0 = j0cat; }
  else        { outf = outP; outld = NM; j0 = j0cat - 2048; }

  const int l15 = l & 15, l16 = l >> 4;
  const int srow8 = l >> 3;
  const int scb   = (l & 7) << 4;

  const float al = alpha_const();

  __shared__ __align__(1024) ushort_t ldsA[2][256 * 64];
  __shared__ __align__(1024) ushort_t ldsB[2][BN * 64];

  f32x4 acc[8][NFR];
#pragma unroll
  for (int m = 0; m < 8; ++m)
#pragma unroll
    for (int n = 0; n < NFR; ++n)
      acc[m][n] = (f32x4){0.f, 0.f, 0.f, 0.f};
  bf16x8 Bf[NFR][2];

  auto SH2 = [&](ushort_t* lb, const ushort_t* g0) {   // 128-row half
#pragma unroll
    for (int c = 0; c < 2; ++c) {
      const int row = (w * 2 + c) * 8 + srow8;
      const int sc = (scb ^ ((row & 7) << 4)) >> 1;
      gload_lds16(g0 + (size_t)row * (size_t)KK + sc, lb + (w * 2 + c) * 512);
    }
  };
  auto stA = [&](int buf, int half, int kt) {
    SH2(&ldsA[buf][half * (128 * 64)],
        Aop + (size_t)(i0 + half * 128) * (size_t)KK + (size_t)kt * 64);
  };
  auto stB = [&](int buf, int half, int kt) {
    SH2(&ldsB[buf][half * (128 * 64)],
        Bcat + (size_t)(j0cat + half * 128) * (size_t)KK + (size_t)kt * 64);
  };
  auto rdA = [&](int buf, int R, int ks) -> bf16x8 {
    const int bc = ((ks * 64 + l16 * 16) ^ ((R & 7) << 4)) >> 1;
    return *(const bf16x8*)&ldsA[buf][R * 64 + bc];
  };
  auto rdB = [&](int buf, int R, int ks) -> bf16x8 {
    const int bc = ((ks * 64 + l16 * 16) ^ ((R & 7) << 4)) >> 1;
    return *(const bf16x8*)&ldsB[buf][R * 64 + bc];
  };

#define VMC_STEADY() asm volatile("s_waitcnt vmcnt(4)" ::: "memory")

#define STOREQ(qd)                                                          \
  do {                                                                      \
    _Pragma("unroll")                                                       \
    for (int mm = 0; mm < 2; ++mm) {                                        \
      const int m = (qd) * 2 + mm;                                          \
      const int gr0 = i0 + wm * 128 + m * 16 + l16 * 4;                     \
      _Pragma("unroll")                                                     \
      for (int n = 0; n < NFR; ++n) {                                       \
        const int gc = j0 + wn * WN + n * 16 + l15;                         \
        _Pragma("unroll")                                                   \
        for (int qq = 0; qq < 4; ++qq) {                                    \
          const size_t idx = (size_t)(gr0 + qq) * (size_t)outld + gc;       \
          outf[idx] = al * acc[m][n][qq];                                   \
        }                                                                   \
      }                                                                     \
    }                                                                       \
  } while (0)

#define PHASE(bufc, q, LB, STG, VM, EPI)                                    \
  do {                                                                      \
    if (LB) {                                                               \
      _Pragma("unroll")                                                     \
      for (int n = 0; n < NFR; ++n) {                                       \
        Bf[n][0] = rdB(bufc, wn * WN + n * 16 + l15, 0);                    \
        Bf[n][1] = rdB(bufc, wn * WN + n * 16 + l15, 1);                    \
      }                                                                     \
    }                                                                       \
    bf16x8 a00 = rdA(bufc, wm * 128 + ((q) * 2 + 0) * 16 + l15, 0);         \
    bf16x8 a01 = rdA(bufc, wm * 128 + ((q) * 2 + 0) * 16 + l15, 1);         \
    bf16x8 a10 = rdA(bufc, wm * 128 + ((q) * 2 + 1) * 16 + l15, 0);         \
    bf16x8 a11 = rdA(bufc, wm * 128 + ((q) * 2 + 1) * 16 + l15, 1);         \
    STG;                                                                    \
    if (LB) asm volatile("s_waitcnt lgkmcnt(8)" ::: "memory");              \
    __builtin_amdgcn_s_barrier();                                           \
    asm volatile("s_waitcnt lgkmcnt(0)" ::: "memory");                      \
    __builtin_amdgcn_sched_barrier(0);                                      \
    __builtin_amdgcn_s_setprio(1);                                          \
    _Pragma("unroll")                                                       \
    for (int n = 0; n < NFR; ++n) {                                         \
      acc[(q) * 2 + 0][n] = __builtin_amdgcn_mfma_f32_16x16x32_bf16(        \
          a00, Bf[n][0], acc[(q) * 2 + 0][n], 0, 0, 0);                     \
      acc[(q) * 2 + 0][n] = __builtin_amdgcn_mfma_f32_16x16x32_bf16(        \
          a01, Bf[n][1], acc[(q) * 2 + 0][n], 0, 0, 0);                     \
      acc[(q) * 2 + 1][n] = __builtin_amdgcn_mfma_f32_16x16x32_bf16(        \
          a10, Bf[n][0], acc[(q) * 2 + 1][n], 0, 0, 0);                     \
      acc[(q) * 2 + 1][n] = __builtin_amdgcn_mfma_f32_16x16x32_bf16(        \
          a11, Bf[n][1], acc[(q) * 2 + 1][n], 0, 0, 0);                     \
    }                                                                       \
    __builtin_amdgcn_s_setprio(0);                                          \
    EPI;                                                                    \
    {                                                                       \
      const int _vm = (VM);                                                 \
      if (_vm == 1) VMC_STEADY();                                           \
      else if (_vm == 2) asm volatile("s_waitcnt vmcnt(0)" ::: "memory");   \
    }                                                                       \
    __builtin_amdgcn_s_barrier();                                           \
    __builtin_amdgcn_sched_barrier(0);                                      \
  } while (0)

  const int nt = KK >> 6;        // 16
  const int nit = nt >> 1;       // 8

  // prologue: buf0 <- tile0 (A+B), buf1.B <- tile1
  stA(0, 0, 0); stA(0, 1, 0); stB(0, 0, 0); stB(0, 1, 0);
  stB(1, 0, 1); stB(1, 1, 1);
  VMC_STEADY();
  __builtin_amdgcn_s_barrier();
  __builtin_amdgcn_sched_barrier(0);

#pragma unroll 1
  for (int it = 0; it < nit - 1; ++it) {
    const int t1 = 2 * it + 1, t2 = 2 * it + 2, t3 = 2 * it + 3;
    PHASE(0, 0, true,  { stA(1, 0, t1); }, 0, );            // ph1
    PHASE(0, 1, false, { stA(1, 1, t1); }, 0, );            // ph2
    PHASE(0, 2, false, { stB(0, 0, t2); }, 0, );            // ph3
    PHASE(0, 3, false, { stB(0, 1, t2); }, 1, );            // ph4
    PHASE(1, 0, true,  { stA(0, 0, t2); }, 0, );            // ph5
    PHASE(1, 1, false, { stA(0, 1, t2); }, 0, );            // ph6
    PHASE(1, 2, false, { stB(1, 0, t3); }, 0, );            // ph7
    PHASE(1, 3, false, { stB(1, 1, t3); }, 1, );            // ph8
  }
  {  // peeled final iteration: stores overlap ph5-8
    const int t1 = nt - 1;
    PHASE(0, 0, true,  { stA(1, 0, t1); }, 0, );
    PHASE(0, 1, false, { stA(1, 1, t1); }, 0, );
    PHASE(0, 2, false, { }, 0, );
    PHASE(0, 3, false, { }, 2, );                           // drain A1
    PHASE(1, 0, true,  { }, 0, STOREQ(0));
    PHASE(1, 1, false, { }, 0, STOREQ(1));
    PHASE(1, 2, false, { }, 0, STOREQ(2));
    PHASE(1, 3, false, { }, 0, STOREQ(3));
  }
#undef PHASE
#undef STOREQ
#undef VMC_STEADY
}

extern "C" void kernel_launch(void* const* d_in, const int* in_sizes, int n_in,
                              void* d_out, int out_size, void* d_ws, size_t ws_size,
                              hipStream_t stream) {
  (void)in_sizes; (void)n_in; (void)out_size; (void)ws_size;
  const float* img = (const float*)d_in[0];   // [8192][1024] f32
  const float* W   = (const float*)d_in[1];   // [1024][2048] f32, cols unit-norm

  float* Rr = (float*)d_out;                   // r = alpha*(img@W), f32 [8192][2048]
  float* Pp = Rr + (size_t)NB * NK;            // pred = alpha*(img@Q), f32 [8192][1024]

  char* ws = (char*)d_ws;
  ushort_t* imgbf = (ushort_t*)(ws + 0);          // 16,777,216 B [8192][1024]
  ushort_t* Wt    = (ushort_t*)(ws + 16777216);   //  4,194,304 B [2048][1024]
  ushort_t* Qbf   = (ushort_t*)(ws + 20971520);   //  2,097,152 B [1024][1024]
  // Bcat = Wt..Qbf contiguous: 3072 rows x 1024 cols bf16

  // prep: img->bf16 (0-511), W->Wt transpose (512-1023), Q from f32 W (1024-1279)
  prep_k<<<1280, 256, 0, stream>>>(img, W, imgbf, Wt, Qbf);

  // fused finals: [r | pred] = alpha * (imgbf @ Bcat^T). 32 x 12 = 384 blocks.
  gemm8ph<<<384, 512, 0, stream>>>(imgbf, Wt, NM, 12, Rr, Pp);
}